// Round 4
// baseline (78.032 us; speedup 1.0000x reference)
//
#include <hip/hip_runtime.h>

// L1 pairwise distance: out[i][j] = sum_d |x1[i][d] - x2[j][d]|
// x1: [2048, 64] f32, x2: [2048, 64] f32, out: [2048, 2048] f32.
// Mean-adjustment in the reference cancels: (x1-adj)-(x2-adj) = x1-x2.
// clamp_min(0) is a no-op on a sum of |.|.
//
// R3: R2 structure (128x64 tile, 8x4/thread, one-shot LDS staging, single
// barrier, 512 blocks = 3/CU at 51KB LDS) with the d-loop unroll BOUNDED
// to 4 chunks: R2's full unroll was ~33KB straight-line code > 32KB L1I.
// Body now ~9KB (1024 VALU + 48 ds_read_b128), looped 4x.
// Poles: VALU 6.8us, LDS 5.8us, write 2.7us -> ~9-10us kernel target.

#define D_FIXED 64
#define BI 128   // x1 rows per block
#define BJ 64    // x2 cols per block
#define PAD 68   // rows stay 16B-aligned; bank shift 4/row -> <=2-way alias (free)

__global__ __launch_bounds__(256, 2)
void l1dist_kernel(const float* __restrict__ x1, const float* __restrict__ x2,
                   float* __restrict__ out, int N1, int N2) {
    __shared__ float s1[BI * PAD];  // 34816 B
    __shared__ float s2[BJ * PAD];  // 17408 B  (51KB total -> 3 blocks/CU)

    const int tx = threadIdx.x;     // 0..15
    const int ty = threadIdx.y;     // 0..15
    const int t  = ty * 16 + tx;
    const int i0 = blockIdx.y * BI;
    const int j0 = blockIdx.x * BJ;

    // ---- one-shot staging (coalesced float4) ----
    const float* g1 = x1 + (size_t)i0 * D_FIXED;
    #pragma unroll
    for (int f = 0; f < 8; ++f) {           // 2048 float4s / 256 threads
        int idx = t + f * 256;
        int row = idx >> 4;
        int c4  = (idx & 15) << 2;
        *(float4*)(s1 + row * PAD + c4) = *(const float4*)(g1 + row * D_FIXED + c4);
    }
    const float* g2 = x2 + (size_t)j0 * D_FIXED;
    #pragma unroll
    for (int f = 0; f < 4; ++f) {           // 1024 float4s / 256 threads
        int idx = t + f * 256;
        int row = idx >> 4;
        int c4  = (idx & 15) << 2;
        *(float4*)(s2 + row * PAD + c4) = *(const float4*)(g2 + row * D_FIXED + c4);
    }
    __syncthreads();                         // the ONLY barrier

    // ---- 8x4 register tile: rows i = ty+16r, cols j = tx+16c ----
    float acc[8][4];
    #pragma unroll
    for (int r = 0; r < 8; ++r)
        #pragma unroll
        for (int c = 0; c < 4; ++c) acc[r][c] = 0.0f;

    // Bounded unroll: 4 chunks/iter -> ~9KB body, fits 32KB L1I (R2 overflowed).
    #pragma unroll 4
    for (int d = 0; d < D_FIXED; d += 4) {
        float4 a[8], b[4];
        #pragma unroll
        for (int c = 0; c < 4; ++c)          // <=2-way bank alias (free)
            b[c] = *(const float4*)(s2 + (tx + 16 * c) * PAD + d);
        #pragma unroll
        for (int r = 0; r < 8; ++r)          // wave-broadcast (4 addrs/wave)
            a[r] = *(const float4*)(s1 + (ty + 16 * r) * PAD + d);

        #pragma unroll
        for (int r = 0; r < 8; ++r) {
            #pragma unroll
            for (int c = 0; c < 4; ++c) {
                float d0 = a[r].x - b[c].x;
                float d1 = a[r].y - b[c].y;
                float d2 = a[r].z - b[c].z;
                float d3 = a[r].w - b[c].w;
                // abs folds into v_add_f32 input modifiers: 8 VALU per 4 elems
                acc[r][c] += (fabsf(d0) + fabsf(d1)) + (fabsf(d2) + fabsf(d3));
            }
        }
    }

    // ---- store: per (r,c) a wave writes 4x 64B full cache lines ----
    #pragma unroll
    for (int r = 0; r < 8; ++r) {
        const size_t i = i0 + ty + 16 * r;
        #pragma unroll
        for (int c = 0; c < 4; ++c) {
            const int j = j0 + tx + 16 * c;
            out[i * N2 + j] = acc[r][c];
        }
    }
}

extern "C" void kernel_launch(void* const* d_in, const int* in_sizes, int n_in,
                              void* d_out, int out_size, void* d_ws, size_t ws_size,
                              hipStream_t stream) {
    const float* x1 = (const float*)d_in[0];
    const float* x2 = (const float*)d_in[1];
    float* out = (float*)d_out;

    const int N1 = in_sizes[0] / D_FIXED;  // 2048
    const int N2 = in_sizes[1] / D_FIXED;  // 2048

    dim3 block(16, 16);
    dim3 grid(N2 / BJ, N1 / BI);           // (32, 16) = 512 blocks, 3/CU resident
    l1dist_kernel<<<grid, block, 0, stream>>>(x1, x2, out, N1, N2);
}

// Round 5
// 69.831 us; speedup vs baseline: 1.1174x; 1.1174x over previous
//
#include <hip/hip_runtime.h>

// L1 pairwise distance: out[i][j] = sum_d |x1[i][d] - x2[j][d]|
// x1: [2048, 64] f32, x2: [2048, 64] f32, out: [2048, 2048] f32.
// Mean-adjustment in the reference cancels: (x1-adj)-(x2-adj) = x1-x2.
// clamp_min(0) is a no-op on a sum of |.|.
//
// R4 = R2 (best measured, 70.87us) restored: 128x64 block tile, 8x4 per
// thread, one-shot LDS staging, ONE barrier, FULL d-unroll (bounding it to
// 4 regressed: R3 78.0us). Micro-changes: b-loads before a-loads, and
// nontemporal stores for the write-once output.
// Model: VALU floor 6.8us, LDS 402MB ~5.8us, write 16MB ~2.7us -> ~10us
// kernel under a ~60us harness floor (268MB ws re-poison fill = 41.5us).

#define D_FIXED 64
#define BI 128   // x1 rows per block
#define BJ 64    // x2 cols per block
#define PAD 68   // rows 16B-aligned; bank shift 4/row -> <=2-way alias (free, m136)

__global__ __launch_bounds__(256, 2)
void l1dist_kernel(const float* __restrict__ x1, const float* __restrict__ x2,
                   float* __restrict__ out, int N1, int N2) {
    __shared__ float s1[BI * PAD];  // 34816 B
    __shared__ float s2[BJ * PAD];  // 17408 B  (51KB total)

    const int tx = threadIdx.x;     // 0..15
    const int ty = threadIdx.y;     // 0..15
    const int t  = ty * 16 + tx;
    const int i0 = blockIdx.y * BI;
    const int j0 = blockIdx.x * BJ;

    // ---- one-shot staging (coalesced float4) ----
    const float* g1 = x1 + (size_t)i0 * D_FIXED;
    #pragma unroll
    for (int f = 0; f < 8; ++f) {           // 2048 float4s / 256 threads
        int idx = t + f * 256;
        int row = idx >> 4;
        int c4  = (idx & 15) << 2;
        *(float4*)(s1 + row * PAD + c4) = *(const float4*)(g1 + row * D_FIXED + c4);
    }
    const float* g2 = x2 + (size_t)j0 * D_FIXED;
    #pragma unroll
    for (int f = 0; f < 4; ++f) {           // 1024 float4s / 256 threads
        int idx = t + f * 256;
        int row = idx >> 4;
        int c4  = (idx & 15) << 2;
        *(float4*)(s2 + row * PAD + c4) = *(const float4*)(g2 + row * D_FIXED + c4);
    }
    __syncthreads();                         // the ONLY barrier

    // ---- 8x4 register tile: rows i = ty+16r, cols j = tx+16c ----
    float acc[8][4];
    #pragma unroll
    for (int r = 0; r < 8; ++r)
        #pragma unroll
        for (int c = 0; c < 4; ++c) acc[r][c] = 0.0f;

    #pragma unroll
    for (int d = 0; d < D_FIXED; d += 4) {   // FULL unroll (R3's bound regressed)
        float4 a[8], b[4];
        #pragma unroll
        for (int c = 0; c < 4; ++c)          // <=2-way bank alias (free)
            b[c] = *(const float4*)(s2 + (tx + 16 * c) * PAD + d);
        #pragma unroll
        for (int r = 0; r < 8; ++r)          // wave-broadcast (4 addrs/wave)
            a[r] = *(const float4*)(s1 + (ty + 16 * r) * PAD + d);

        #pragma unroll
        for (int r = 0; r < 8; ++r) {
            #pragma unroll
            for (int c = 0; c < 4; ++c) {
                float d0 = a[r].x - b[c].x;
                float d1 = a[r].y - b[c].y;
                float d2 = a[r].z - b[c].z;
                float d3 = a[r].w - b[c].w;
                // abs folds into v_add_f32 input modifiers: 8 VALU per 4 elems
                acc[r][c] += (fabsf(d0) + fabsf(d1)) + (fabsf(d2) + fabsf(d3));
            }
        }
    }

    // ---- store: write-once output -> nontemporal; 64B segments per line ----
    #pragma unroll
    for (int r = 0; r < 8; ++r) {
        const size_t i = i0 + ty + 16 * r;
        #pragma unroll
        for (int c = 0; c < 4; ++c) {
            const int j = j0 + tx + 16 * c;
            __builtin_nontemporal_store(acc[r][c], &out[i * N2 + j]);
        }
    }
}

extern "C" void kernel_launch(void* const* d_in, const int* in_sizes, int n_in,
                              void* d_out, int out_size, void* d_ws, size_t ws_size,
                              hipStream_t stream) {
    const float* x1 = (const float*)d_in[0];
    const float* x2 = (const float*)d_in[1];
    float* out = (float*)d_out;

    const int N1 = in_sizes[0] / D_FIXED;  // 2048
    const int N2 = in_sizes[1] / D_FIXED;  // 2048

    dim3 block(16, 16);
    dim3 grid(N2 / BJ, N1 / BI);           // (32, 16) = 512 blocks = 2/CU
    l1dist_kernel<<<grid, block, 0, stream>>>(x1, x2, out, N1, N2);
}